// Round 1
// baseline (1212.072 us; speedup 1.0000x reference)
//
#include <hip/hip_runtime.h>

// RelationalDelayGNNStage: N=20000 nodes, E=500000 edges, D=256, T=4, NTYPES=3, NU=1
// Strategy: aggregate-first (linearity: seg(mask*(x@W+b)[src]) = seg(mask*x[src])@W + cnt*b)
//   1) build CSR by dst (histogram + scan + scatter), per-channel counts for bias
//   2) per step s: one edge pass -> etype aggregates A[3] + hop aggregates C_k[s]
//   3) per step t: fused GEMM  x = x + relu(sum_c agg_c @ W_c + cnt_c * b_c)

#define NN 20000
#define NE 500000
#define DD 256
#define TT 4
#define NT 3

__device__ inline void f4add(float4& a, const float4 b) {
  a.x += b.x; a.y += b.y; a.z += b.z; a.w += b.w;
}

// ---------------- CSR build ----------------

__global__ void k_hist(const int* __restrict__ ei, const int* __restrict__ ea,
                       int* __restrict__ deg, int* __restrict__ cnt) {
  int e = blockIdx.x * 256 + threadIdx.x;
  if (e >= NE) return;
  int dst = ei[NE + e];
  atomicAdd(&deg[dst], 1);
  int hop = ea[2 * e];      // edge_attr[e][0]
  int et  = ea[2 * e + 1];  // edge_attr[e][1]
  atomicAdd(&cnt[et * NN + dst], 1);
  if (hop >= 2) atomicAdd(&cnt[(3 + hop - 2) * NN + dst], 1);
}

__global__ void k_scan(const int* __restrict__ deg, int* __restrict__ row_ptr,
                       int* __restrict__ cursor) {
  __shared__ int sdata[1024];
  __shared__ int s_run;
  int tid = threadIdx.x;
  if (tid == 0) s_run = 0;
  __syncthreads();
  for (int base = 0; base < NN; base += 1024) {
    int i = base + tid;
    int v = (i < NN) ? deg[i] : 0;
    sdata[tid] = v;
    __syncthreads();
    for (int off = 1; off < 1024; off <<= 1) {
      int t = (tid >= off) ? sdata[tid - off] : 0;
      __syncthreads();
      sdata[tid] += t;
      __syncthreads();
    }
    int excl = s_run + sdata[tid] - v;
    if (i < NN) { row_ptr[i] = excl; cursor[i] = excl; }
    __syncthreads();
    if (tid == 1023) s_run += sdata[1023];
    __syncthreads();
  }
  if (tid == 0) row_ptr[NN] = s_run;
}

__global__ void k_scatter(const int* __restrict__ ei, const int* __restrict__ ea,
                          int* __restrict__ cursor, int* __restrict__ records) {
  int e = blockIdx.x * 256 + threadIdx.x;
  if (e >= NE) return;
  int src = ei[e];
  int dst = ei[NE + e];
  int hop = ea[2 * e];
  int et  = ea[2 * e + 1];
  int pos = atomicAdd(&cursor[dst], 1);
  // pack: src [0..17], hop-1 [18..19], etype [20..21]
  records[pos] = src | ((hop - 1) << 18) | (et << 20);
}

// ---------------- aggregation: one wave per node ----------------

__global__ __launch_bounds__(256) void k_aggregate(
    const float* __restrict__ x,
    const int* __restrict__ row_ptr,
    const int* __restrict__ records,
    float* __restrict__ aggA,  // 3 stacked N*D tensors (etype 0..2)
    float* __restrict__ c2p,   // hop==2 aggregate (or null)
    float* __restrict__ c3p,   // hop==3 aggregate (or null)
    float* __restrict__ c4p)   // hop==4 aggregate (or null)
{
  int wave = threadIdx.x >> 6;
  int lane = threadIdx.x & 63;
  int v = blockIdx.x * 4 + wave;
  if (v >= NN) return;
  int beg = row_ptr[v], end = row_ptr[v + 1];
  float4 a0 = make_float4(0, 0, 0, 0), a1 = a0, a2 = a0;
  float4 c2 = a0, c3 = a0, c4 = a0;
  for (int e = beg; e < end; ++e) {
    int rec = records[e];
    int src   = rec & 0x3FFFF;
    int hopm2 = ((rec >> 18) & 3) - 1;  // hop-2: -1..2
    int et    = (rec >> 20) & 3;
    float4 xv = *(const float4*)(x + (size_t)src * DD + (lane << 2));
    if (et == 0)      f4add(a0, xv);
    else if (et == 1) f4add(a1, xv);
    else              f4add(a2, xv);
    if (hopm2 == 0)      f4add(c2, xv);
    else if (hopm2 == 1) f4add(c3, xv);
    else if (hopm2 == 2) f4add(c4, xv);
  }
  size_t o = (size_t)v * DD + (lane << 2);
  *(float4*)(aggA + o) = a0;
  *(float4*)(aggA + (size_t)NN * DD + o) = a1;
  *(float4*)(aggA + 2 * (size_t)NN * DD + o) = a2;
  if (c2p) *(float4*)(c2p + o) = c2;
  if (c3p) *(float4*)(c3p + o) = c3;
  if (c4p) *(float4*)(c4p + o) = c4;
}

// ---------------- fused multi-channel GEMM + bias + relu + residual ----------------

struct GemmArgs {
  const float* A[6];
  const float* W[6];
  const float* bias[6];
  const int*   cnt[6];
  int nch;
  const float* x_in;
  float*       x_out;
};

#define TM 64
#define TN 64
#define KB 16

__global__ __launch_bounds__(256) void k_gemm(GemmArgs args) {
  __shared__ float As[KB][TM + 4];
  __shared__ float Bs[KB][TN];
  int tid = threadIdx.x;
  int tx = tid & 15;   // n dir (4 cols each)
  int ty = tid >> 4;   // m dir (4 rows each)
  int m0 = blockIdx.x * TM;
  int n0 = blockIdx.y * TN;

  float acc[4][4];
#pragma unroll
  for (int i = 0; i < 4; i++)
#pragma unroll
    for (int j = 0; j < 4; j++) acc[i][j] = 0.f;

  for (int c = 0; c < args.nch; ++c) {
    const float* A = args.A[c];
    const float* W = args.W[c];
    for (int kb = 0; kb < DD; kb += KB) {
      // stage A tile: 64 rows x 16 k, one float4 per thread (transpose into LDS)
      {
        int m = tid >> 2;
        int k4 = (tid & 3) * 4;
        int gm = m0 + m;
        float4 av = (gm < NN) ? *(const float4*)(A + (size_t)gm * DD + kb + k4)
                              : make_float4(0, 0, 0, 0);
        As[k4 + 0][m] = av.x; As[k4 + 1][m] = av.y;
        As[k4 + 2][m] = av.z; As[k4 + 3][m] = av.w;
      }
      // stage B tile: 16 k x 64 n, one float4 per thread
      {
        int k = tid >> 4;
        int n4 = (tid & 15) * 4;
        float4 bv = *(const float4*)(W + (size_t)(kb + k) * DD + n0 + n4);
        *(float4*)&Bs[k][n4] = bv;
      }
      __syncthreads();
#pragma unroll
      for (int kk = 0; kk < KB; ++kk) {
        float4 a4 = *(const float4*)&As[kk][ty * 4];
        float4 b4 = *(const float4*)&Bs[kk][tx * 4];
        float a[4] = {a4.x, a4.y, a4.z, a4.w};
        float b[4] = {b4.x, b4.y, b4.z, b4.w};
#pragma unroll
        for (int i = 0; i < 4; i++)
#pragma unroll
          for (int j = 0; j < 4; j++) acc[i][j] += a[i] * b[j];
      }
      __syncthreads();
    }
  }

  // bias: acc[i][j] += cnt_c[m] * b_c[n]
  for (int c = 0; c < args.nch; ++c) {
    const int* cntp = args.cnt[c];
    const float* bp = args.bias[c];
    float bv[4];
#pragma unroll
    for (int j = 0; j < 4; j++) bv[j] = bp[n0 + tx * 4 + j];
#pragma unroll
    for (int i = 0; i < 4; i++) {
      int gm = m0 + ty * 4 + i;
      float cv = (gm < NN) ? (float)cntp[gm] : 0.f;
#pragma unroll
      for (int j = 0; j < 4; j++) acc[i][j] += cv * bv[j];
    }
  }

  // epilogue: x_out = x_in + relu(acc)
#pragma unroll
  for (int i = 0; i < 4; i++) {
    int gm = m0 + ty * 4 + i;
    if (gm >= NN) continue;
    size_t off = (size_t)gm * DD + n0 + tx * 4;
    float4 xv = *(const float4*)(args.x_in + off);
    float4 o;
    o.x = xv.x + fmaxf(acc[i][0], 0.f);
    o.y = xv.y + fmaxf(acc[i][1], 0.f);
    o.z = xv.z + fmaxf(acc[i][2], 0.f);
    o.w = xv.w + fmaxf(acc[i][3], 0.f);
    *(float4*)(args.x_out + off) = o;
  }
}

// ---------------- host ----------------

extern "C" void kernel_launch(void* const* d_in, const int* in_sizes, int n_in,
                              void* d_out, int out_size, void* d_ws, size_t ws_size,
                              hipStream_t stream) {
  const float* x      = (const float*)d_in[0];
  const int* edge_index = (const int*)d_in[1];
  const int* edge_attr  = (const int*)d_in[2];
  const float* W_edge = (const float*)d_in[3];
  const float* b_edge = (const float*)d_in[4];
  const float* W_hop  = (const float*)d_in[5];
  const float* b_hop  = (const float*)d_in[6];
  float* out = (float*)d_out;

  // workspace layout
  char* ws = (char*)d_ws;
  int* deg     = (int*)ws;            // N
  int* cnt     = deg + NN;            // 6N  (etype 0..2, hop2,hop3,hop4)
  int* row_ptr = cnt + 6 * NN;        // N+1
  int* cursor  = row_ptr + (NN + 1);  // N
  int* records = cursor + NN;         // E
  size_t int_count = (size_t)NN + 6 * NN + (NN + 1) + NN + NE;
  float* fbase = (float*)(ws + ((int_count * 4 + 255) & ~(size_t)255));
  const size_t ND = (size_t)NN * DD;
  float* x_cur = fbase;            // N*D
  float* A_buf = x_cur + ND;       // 3*N*D (etype aggregates, reused per step)
  float* Cb[6];                    // C2_s0,C2_s1,C2_s2, C3_s0,C3_s1, C4_s0
  {
    float* p = A_buf + 3 * ND;
    for (int i = 0; i < 6; i++) { Cb[i] = p; p += ND; }
  }

  hipMemsetAsync(deg, 0, 7 * NN * sizeof(int), stream);  // deg + cnt (adjacent)
  hipMemcpyAsync(x_cur, x, ND * sizeof(float), hipMemcpyDeviceToDevice, stream);

  k_hist<<<(NE + 255) / 256, 256, 0, stream>>>(edge_index, edge_attr, deg, cnt);
  k_scan<<<1, 1024, 0, stream>>>(deg, row_ptr, cursor);
  k_scatter<<<(NE + 255) / 256, 256, 0, stream>>>(edge_index, edge_attr, cursor, records);

  // C2[s] = Cb[s] (s=0..2), C3[s] = Cb[3+s] (s=0..1), C4[0] = Cb[5]
  for (int t = 0; t < TT; ++t) {
    float* c2p = (t <= 2) ? Cb[t]     : nullptr;
    float* c3p = (t <= 1) ? Cb[3 + t] : nullptr;
    float* c4p = (t == 0) ? Cb[5]     : nullptr;
    k_aggregate<<<NN / 4, 256, 0, stream>>>(x_cur, row_ptr, records, A_buf, c2p, c3p, c4p);

    GemmArgs ga{};
    for (int e = 0; e < NT; ++e) {
      ga.A[e]    = A_buf + (size_t)e * ND;
      ga.W[e]    = W_edge + (size_t)(t * NT + e) * DD * DD;
      ga.bias[e] = b_edge + (size_t)(t * NT + e) * DD;
      ga.cnt[e]  = cnt + (size_t)e * NN;
    }
    int nc = NT;
    for (int k = 2; k <= t + 1; ++k) {
      int s = t + 1 - k;  // source step whose aggregate we consume
      ga.A[nc]    = (k == 2) ? Cb[s] : (k == 3) ? Cb[3 + s] : Cb[5];
      ga.W[nc]    = W_hop + (size_t)(t * (TT - 1) + (k - 2)) * DD * DD;
      ga.bias[nc] = b_hop + (size_t)(t * (TT - 1) + (k - 2)) * DD;
      ga.cnt[nc]  = cnt + (size_t)(3 + (k - 2)) * NN;
      nc++;
    }
    ga.nch = nc;
    ga.x_in = x_cur;
    ga.x_out = (t == TT - 1) ? out : x_cur;
    k_gemm<<<dim3((NN + TM - 1) / TM, DD / TN), 256, 0, stream>>>(ga);
  }
}

// Round 2
// 906.869 us; speedup vs baseline: 1.3365x; 1.3365x over previous
//
#include <hip/hip_runtime.h>

// RelationalDelayGNNStage: N=20000, E=500000, D=256, T=4, NTYPES=3
// Round 2: aggregate-first + fp16 SPLIT-PRECISION MFMA GEMM.
//   A = Ahi+Alo (fp16, scale 2^-6), W = Whi+Wlo (fp16, scale 2^10, pre-transposed)
//   A@W = (Ahi@Whi + Ahi@Wlo + Alo@Whi) * 2^-4   (error ~2^-22 rel/layer ~ fp32 noise)
// GEMM: m97 structure — 128x128 tile, BK=32, global_load_lds(16B), 16x16x32 f16 MFMA.

#define NN 20000
#define NE 500000
#define DD 256
#define TT 4
#define NT 3
#define BK 32

typedef _Float16 f16;
typedef _Float16 f16x8 __attribute__((ext_vector_type(8)));
typedef _Float16 f16x4v __attribute__((ext_vector_type(4)));
typedef float f32x4 __attribute__((ext_vector_type(4)));

typedef const __attribute__((address_space(1))) void* gptr_t;
typedef __attribute__((address_space(3))) void* lptr_t;

__device__ __forceinline__ void gll16(const void* g, void* l) {
  __builtin_amdgcn_global_load_lds((gptr_t)g, (lptr_t)l, 16, 0, 0);
}

__device__ inline void f4add(float4& a, const float4 b) {
  a.x += b.x; a.y += b.y; a.z += b.z; a.w += b.w;
}

// ---------------- CSR build ----------------

__global__ void k_hist(const int* __restrict__ ei, const int* __restrict__ ea,
                       int* __restrict__ deg, int* __restrict__ cnt) {
  int e = blockIdx.x * 256 + threadIdx.x;
  if (e >= NE) return;
  int dst = ei[NE + e];
  atomicAdd(&deg[dst], 1);
  int hop = ea[2 * e];
  int et  = ea[2 * e + 1];
  atomicAdd(&cnt[et * NN + dst], 1);
  if (hop >= 2) atomicAdd(&cnt[(3 + hop - 2) * NN + dst], 1);
}

__global__ void k_scan(const int* __restrict__ deg, int* __restrict__ row_ptr,
                       int* __restrict__ cursor) {
  __shared__ int sdata[1024];
  __shared__ int s_run;
  int tid = threadIdx.x;
  if (tid == 0) s_run = 0;
  __syncthreads();
  for (int base = 0; base < NN; base += 1024) {
    int i = base + tid;
    int v = (i < NN) ? deg[i] : 0;
    sdata[tid] = v;
    __syncthreads();
    for (int off = 1; off < 1024; off <<= 1) {
      int t = (tid >= off) ? sdata[tid - off] : 0;
      __syncthreads();
      sdata[tid] += t;
      __syncthreads();
    }
    int excl = s_run + sdata[tid] - v;
    if (i < NN) { row_ptr[i] = excl; cursor[i] = excl; }
    __syncthreads();
    if (tid == 1023) s_run += sdata[1023];
    __syncthreads();
  }
  if (tid == 0) row_ptr[NN] = s_run;
}

__global__ void k_scatter(const int* __restrict__ ei, const int* __restrict__ ea,
                          int* __restrict__ cursor, int* __restrict__ records) {
  int e = blockIdx.x * 256 + threadIdx.x;
  if (e >= NE) return;
  int src = ei[e];
  int dst = ei[NE + e];
  int hop = ea[2 * e];
  int et  = ea[2 * e + 1];
  int pos = atomicAdd(&cursor[dst], 1);
  records[pos] = src | ((hop - 1) << 18) | (et << 20);
}

// ---------------- W split: fp32 -> transposed fp16 hi/lo, scale 2^10 ----------------
// Wout: 24 matrices, each 2*65536 f16: [hi: Wt[n][k]] [lo: Wt[n][k]]

__global__ void k_wsplit(const float* __restrict__ W_edge, const float* __restrict__ W_hop,
                         f16* __restrict__ Wout) {
  int w = blockIdx.y;
  int flat = blockIdx.x * 256 + threadIdx.x;  // 0..65535
  int k = flat & 255, n = flat >> 8;
  const float* src = (w < 12) ? (W_edge + (size_t)w * 65536)
                              : (W_hop + (size_t)(w - 12) * 65536);
  float v = src[k * 256 + n] * 1024.0f;
  f16 hi = (f16)v;
  f16 lo = (f16)(v - (float)hi);
  f16* dst = Wout + (size_t)w * 131072;
  dst[n * 256 + k] = hi;            // consecutive tid -> consecutive k: coalesced write
  dst[65536 + n * 256 + k] = lo;
}

// ---------------- aggregation: one wave per node, fp16 hi/lo output ----------------

__device__ inline void store_split(f16* __restrict__ hi, f16* __restrict__ lo, float4 v) {
  const float s = 0.015625f;  // 2^-6
  float a = v.x * s, b = v.y * s, c = v.z * s, d = v.w * s;
  f16x4v h = { (f16)a, (f16)b, (f16)c, (f16)d };
  f16x4v l = { (f16)(a - (float)h.x), (f16)(b - (float)h.y),
               (f16)(c - (float)h.z), (f16)(d - (float)h.w) };
  *(f16x4v*)hi = h;
  *(f16x4v*)lo = l;
}

__global__ __launch_bounds__(256) void k_aggregate(
    const float* __restrict__ x,
    const int* __restrict__ row_ptr,
    const int* __restrict__ records,
    f16* __restrict__ e0, f16* __restrict__ e1, f16* __restrict__ e2,
    f16* __restrict__ c2p, f16* __restrict__ c3p, f16* __restrict__ c4p)
{
  const size_t ND = (size_t)NN * DD;
  int wave = threadIdx.x >> 6;
  int lane = threadIdx.x & 63;
  int v = blockIdx.x * 4 + wave;
  if (v >= NN) return;
  int beg = row_ptr[v], end = row_ptr[v + 1];
  float4 a0 = make_float4(0, 0, 0, 0), a1 = a0, a2 = a0;
  float4 c2 = a0, c3 = a0, c4 = a0;
  for (int e = beg; e < end; ++e) {
    int rec = records[e];
    int src   = rec & 0x3FFFF;
    int hopm2 = ((rec >> 18) & 3) - 1;
    int et    = (rec >> 20) & 3;
    float4 xv = *(const float4*)(x + (size_t)src * DD + (lane << 2));
    if (et == 0)      f4add(a0, xv);
    else if (et == 1) f4add(a1, xv);
    else              f4add(a2, xv);
    if (hopm2 == 0)      f4add(c2, xv);
    else if (hopm2 == 1) f4add(c3, xv);
    else if (hopm2 == 2) f4add(c4, xv);
  }
  size_t o = (size_t)v * DD + (lane << 2);
  store_split(e0 + o, e0 + ND + o, a0);
  store_split(e1 + o, e1 + ND + o, a1);
  store_split(e2 + o, e2 + ND + o, a2);
  if (c2p) store_split(c2p + o, c2p + ND + o, c2);
  if (c3p) store_split(c3p + o, c3p + ND + o, c3);
  if (c4p) store_split(c4p + o, c4p + ND + o, c4);
}

// ---------------- split-fp16 MFMA GEMM + bias + relu + residual ----------------

struct GemmArgs {
  const f16* A[6];     // hi at +0, lo at +N*D
  const f16* W[6];     // transposed: hi at +0, lo at +D*D
  const float* bias[6];
  const int*   cnt[6];
  int nch;
  const float* x_in;
  float*       x_out;
};

__global__ __launch_bounds__(256, 2) void k_gemm(GemmArgs args) {
  __shared__ __align__(16) f16 sAhi[128 * BK];
  __shared__ __align__(16) f16 sAlo[128 * BK];
  __shared__ __align__(16) f16 sBhi[128 * BK];
  __shared__ __align__(16) f16 sBlo[128 * BK];
  const int tid = threadIdx.x;
  const int lane = tid & 63;
  const int wave = tid >> 6;
  const int wm = (wave >> 1) * 64;
  const int wn = (wave & 1) * 64;
  const int m0 = blockIdx.x * 128;
  const int n0 = blockIdx.y * 128;
  const int nch = args.nch;

  f32x4 acc[4][4];
#pragma unroll
  for (int i = 0; i < 4; i++)
#pragma unroll
    for (int j = 0; j < 4; j++) acc[i][j] = (f32x4){0.f, 0.f, 0.f, 0.f};

  // staging geometry: tile = 128 rows x 32 f16 (64B/row); 2 issues of 16B per tile
  const int r0 = tid >> 2;                 // row within 64-row half
  const int cbo = (tid & 3) * 16;          // byte offset within 64B row
  const int arow0 = min(m0 + r0, NN - 1);
  const int arow1 = min(m0 + 64 + r0, NN - 1);
  const int brow0 = n0 + r0;
  const int brow1 = n0 + 64 + r0;

  char* dA0 = (char*)sAhi + tid * 16;  char* dA1 = (char*)sAhi + 4096 + tid * 16;
  char* dL0 = (char*)sAlo + tid * 16;  char* dL1 = (char*)sAlo + 4096 + tid * 16;
  char* dB0 = (char*)sBhi + tid * 16;  char* dB1 = (char*)sBhi + 4096 + tid * 16;
  char* dM0 = (char*)sBlo + tid * 16;  char* dM1 = (char*)sBlo + 4096 + tid * 16;

  const int khalf8 = (lane >> 4) * 8;      // k offset (f16 elems) of this lane's frag
  const int fr = lane & 15;

  for (int c = 0; c < nch; ++c) {
    const char* Ah = (const char*)args.A[c];
    const char* Al = Ah + (size_t)NN * DD * 2;
    const char* Bh = (const char*)args.W[c];
    const char* Bl = Bh + (size_t)DD * DD * 2;
    const char* pa0 = Ah + (size_t)arow0 * 512 + cbo;
    const char* pa1 = Ah + (size_t)arow1 * 512 + cbo;
    const char* la0 = Al + (size_t)arow0 * 512 + cbo;
    const char* la1 = Al + (size_t)arow1 * 512 + cbo;
    const char* pb0 = Bh + (size_t)brow0 * 512 + cbo;
    const char* pb1 = Bh + (size_t)brow1 * 512 + cbo;
    const char* lb0 = Bl + (size_t)brow0 * 512 + cbo;
    const char* lb1 = Bl + (size_t)brow1 * 512 + cbo;
    for (int kb = 0; kb < DD * 2; kb += BK * 2) {  // byte offset along k
      gll16(pa0 + kb, dA0);  gll16(pa1 + kb, dA1);
      gll16(la0 + kb, dL0);  gll16(la1 + kb, dL1);
      gll16(pb0 + kb, dB0);  gll16(pb1 + kb, dB1);
      gll16(lb0 + kb, dM0);  gll16(lb1 + kb, dM1);
      __syncthreads();
      f16x8 fAh[4], fAl[4], fBh[4], fBl[4];
#pragma unroll
      for (int i = 0; i < 4; i++) {
        int ra = (wm + i * 16 + fr) * BK + khalf8;
        int rb = (wn + i * 16 + fr) * BK + khalf8;
        fAh[i] = *(const f16x8*)&sAhi[ra];
        fAl[i] = *(const f16x8*)&sAlo[ra];
        fBh[i] = *(const f16x8*)&sBhi[rb];
        fBl[i] = *(const f16x8*)&sBlo[rb];
      }
#pragma unroll
      for (int mi = 0; mi < 4; mi++)
#pragma unroll
        for (int ni = 0; ni < 4; ni++) {
          acc[mi][ni] = __builtin_amdgcn_mfma_f32_16x16x32_f16(fAh[mi], fBh[ni], acc[mi][ni], 0, 0, 0);
          acc[mi][ni] = __builtin_amdgcn_mfma_f32_16x16x32_f16(fAh[mi], fBl[ni], acc[mi][ni], 0, 0, 0);
          acc[mi][ni] = __builtin_amdgcn_mfma_f32_16x16x32_f16(fAl[mi], fBh[ni], acc[mi][ni], 0, 0, 0);
        }
      __syncthreads();
    }
  }

  // epilogue: out = x + relu(acc*2^-4 + sum_c cnt_c[row]*b_c[col])
  const float scale = 0.0625f;
  float bcol[4][6];
#pragma unroll
  for (int ni = 0; ni < 4; ni++) {
    int gcol = n0 + wn + ni * 16 + fr;
#pragma unroll
    for (int c = 0; c < 6; c++)
      bcol[ni][c] = (c < nch) ? args.bias[c][gcol] : 0.f;
  }
  const int rowq = (lane >> 4) * 4;
#pragma unroll
  for (int mi = 0; mi < 4; mi++) {
#pragma unroll
    for (int r = 0; r < 4; r++) {
      int grow = m0 + wm + mi * 16 + rowq + r;
      if (grow >= NN) continue;
      float cv[6];
#pragma unroll
      for (int c = 0; c < 6; c++)
        cv[c] = (c < nch) ? (float)args.cnt[c][grow] : 0.f;
      size_t rowoff = (size_t)grow * DD;
#pragma unroll
      for (int ni = 0; ni < 4; ni++) {
        int gcol = n0 + wn + ni * 16 + fr;
        float v = acc[mi][ni][r] * scale;
#pragma unroll
        for (int c = 0; c < 6; c++) v += cv[c] * bcol[ni][c];
        float xv = args.x_in[rowoff + gcol];
        args.x_out[rowoff + gcol] = xv + fmaxf(v, 0.f);
      }
    }
  }
}

// ---------------- host ----------------

extern "C" void kernel_launch(void* const* d_in, const int* in_sizes, int n_in,
                              void* d_out, int out_size, void* d_ws, size_t ws_size,
                              hipStream_t stream) {
  const float* x      = (const float*)d_in[0];
  const int* edge_index = (const int*)d_in[1];
  const int* edge_attr  = (const int*)d_in[2];
  const float* W_edge = (const float*)d_in[3];
  const float* b_edge = (const float*)d_in[4];
  const float* W_hop  = (const float*)d_in[5];
  const float* b_hop  = (const float*)d_in[6];
  float* out = (float*)d_out;

  // workspace layout
  char* ws = (char*)d_ws;
  int* deg     = (int*)ws;            // N
  int* cnt     = deg + NN;            // 6N
  int* row_ptr = cnt + 6 * NN;        // N+1
  int* cursor  = row_ptr + (NN + 1);  // N
  int* records = cursor + NN;         // E
  size_t int_count = (size_t)NN + 6 * NN + (NN + 1) + NN + NE;
  const size_t ND = (size_t)NN * DD;
  f16* Wsplit = (f16*)(ws + ((int_count * 4 + 255) & ~(size_t)255));  // 24 * 131072 f16
  f16* aggBase = Wsplit + (size_t)24 * 131072;
  // 9 aggregate tensors (hi+lo = 2*ND f16 each): 0..2 etype, 3..8 = Cb[0..5]
  f16* agg[9];
  for (int i = 0; i < 9; i++) agg[i] = aggBase + (size_t)i * 2 * ND;
  f16** Cb = agg + 3;  // Cb[0..5]: C2_s0,C2_s1,C2_s2, C3_s0,C3_s1, C4_s0

  hipMemsetAsync(deg, 0, 7 * NN * sizeof(int), stream);
  hipMemcpyAsync(out, x, ND * sizeof(float), hipMemcpyDeviceToDevice, stream);  // x lives in d_out

  k_hist<<<(NE + 255) / 256, 256, 0, stream>>>(edge_index, edge_attr, deg, cnt);
  k_scan<<<1, 1024, 0, stream>>>(deg, row_ptr, cursor);
  k_scatter<<<(NE + 255) / 256, 256, 0, stream>>>(edge_index, edge_attr, cursor, records);
  k_wsplit<<<dim3(256, 24), 256, 0, stream>>>(W_edge, W_hop, Wsplit);

  for (int t = 0; t < TT; ++t) {
    f16* c2p = (t <= 2) ? Cb[t]     : nullptr;
    f16* c3p = (t <= 1) ? Cb[3 + t] : nullptr;
    f16* c4p = (t == 0) ? Cb[5]     : nullptr;
    k_aggregate<<<NN / 4, 256, 0, stream>>>(out, row_ptr, records,
                                            agg[0], agg[1], agg[2], c2p, c3p, c4p);

    GemmArgs ga{};
    for (int e = 0; e < NT; ++e) {
      ga.A[e]    = agg[e];
      ga.W[e]    = Wsplit + (size_t)(t * NT + e) * 131072;
      ga.bias[e] = b_edge + (size_t)(t * NT + e) * DD;
      ga.cnt[e]  = cnt + (size_t)e * NN;
    }
    int nc = NT;
    for (int k = 2; k <= t + 1; ++k) {
      int s = t + 1 - k;
      ga.A[nc]    = (k == 2) ? Cb[s] : (k == 3) ? Cb[3 + s] : Cb[5];
      ga.W[nc]    = Wsplit + (size_t)(12 + t * 3 + (k - 2)) * 131072;
      ga.bias[nc] = b_hop + (size_t)(t * (TT - 1) + (k - 2)) * DD;
      ga.cnt[nc]  = cnt + (size_t)(3 + (k - 2)) * NN;
      nc++;
    }
    // keep unused slots valid (guarded in-kernel, but avoid wild speculative derefs)
    for (int c = nc; c < 6; ++c) {
      ga.A[c] = ga.A[0]; ga.W[c] = ga.W[0]; ga.bias[c] = ga.bias[0]; ga.cnt[c] = ga.cnt[0];
    }
    ga.nch = nc;
    ga.x_in = out;
    ga.x_out = out;
    k_gemm<<<dim3((NN + 127) / 128, 2), 256, 0, stream>>>(ga);
  }
}

// Round 3
// 828.600 us; speedup vs baseline: 1.4628x; 1.0945x over previous
//
#include <hip/hip_runtime.h>

// RelationalDelayGNNStage: N=20000, E=500000, D=256, T=4, NTYPES=3
// Round 3: fix GEMM grid starvation (314 -> 626 blocks; TM 128 -> 64) and LDS
// bank conflicts (XOR chunk swizzle on the global source of global_load_lds).
//   A = Ahi+Alo (fp16, scale 2^-6), W = Whi+Wlo (fp16, scale 2^10, pre-transposed)
//   A@W = (Ahi@Whi + Ahi@Wlo + Alo@Whi) * 2^-4

#define NN 20000
#define NE 500000
#define DD 256
#define TT 4
#define NT 3
#define BK 32

typedef _Float16 f16;
typedef _Float16 f16x8 __attribute__((ext_vector_type(8)));
typedef _Float16 f16x4v __attribute__((ext_vector_type(4)));
typedef float f32x4 __attribute__((ext_vector_type(4)));

typedef const __attribute__((address_space(1))) void* gptr_t;
typedef __attribute__((address_space(3))) void* lptr_t;

__device__ __forceinline__ void gll16(const void* g, void* l) {
  __builtin_amdgcn_global_load_lds((gptr_t)g, (lptr_t)l, 16, 0, 0);
}

__device__ inline void f4add(float4& a, const float4 b) {
  a.x += b.x; a.y += b.y; a.z += b.z; a.w += b.w;
}

// ---------------- CSR build ----------------

__global__ void k_hist(const int* __restrict__ ei, const int* __restrict__ ea,
                       int* __restrict__ deg, int* __restrict__ cnt) {
  int e = blockIdx.x * 256 + threadIdx.x;
  if (e >= NE) return;
  int dst = ei[NE + e];
  atomicAdd(&deg[dst], 1);
  int hop = ea[2 * e];
  int et  = ea[2 * e + 1];
  atomicAdd(&cnt[et * NN + dst], 1);
  if (hop >= 2) atomicAdd(&cnt[(3 + hop - 2) * NN + dst], 1);
}

__global__ void k_scan(const int* __restrict__ deg, int* __restrict__ row_ptr,
                       int* __restrict__ cursor) {
  __shared__ int sdata[1024];
  __shared__ int s_run;
  int tid = threadIdx.x;
  if (tid == 0) s_run = 0;
  __syncthreads();
  for (int base = 0; base < NN; base += 1024) {
    int i = base + tid;
    int v = (i < NN) ? deg[i] : 0;
    sdata[tid] = v;
    __syncthreads();
    for (int off = 1; off < 1024; off <<= 1) {
      int t = (tid >= off) ? sdata[tid - off] : 0;
      __syncthreads();
      sdata[tid] += t;
      __syncthreads();
    }
    int excl = s_run + sdata[tid] - v;
    if (i < NN) { row_ptr[i] = excl; cursor[i] = excl; }
    __syncthreads();
    if (tid == 1023) s_run += sdata[1023];
    __syncthreads();
  }
  if (tid == 0) row_ptr[NN] = s_run;
}

__global__ void k_scatter(const int* __restrict__ ei, const int* __restrict__ ea,
                          int* __restrict__ cursor, int* __restrict__ records) {
  int e = blockIdx.x * 256 + threadIdx.x;
  if (e >= NE) return;
  int src = ei[e];
  int dst = ei[NE + e];
  int hop = ea[2 * e];
  int et  = ea[2 * e + 1];
  int pos = atomicAdd(&cursor[dst], 1);
  records[pos] = src | ((hop - 1) << 18) | (et << 20);
}

// ---------------- W split: fp32 -> transposed fp16 hi/lo, scale 2^10 ----------------

__global__ void k_wsplit(const float* __restrict__ W_edge, const float* __restrict__ W_hop,
                         f16* __restrict__ Wout) {
  int w = blockIdx.y;
  int flat = blockIdx.x * 256 + threadIdx.x;  // 0..65535
  int k = flat & 255, n = flat >> 8;
  const float* src = (w < 12) ? (W_edge + (size_t)w * 65536)
                              : (W_hop + (size_t)(w - 12) * 65536);
  float v = src[k * 256 + n] * 1024.0f;
  f16 hi = (f16)v;
  f16 lo = (f16)(v - (float)hi);
  f16* dst = Wout + (size_t)w * 131072;
  dst[n * 256 + k] = hi;
  dst[65536 + n * 256 + k] = lo;
}

// ---------------- aggregation: one wave per node, fp16 hi/lo output ----------------

__device__ inline void store_split(f16* __restrict__ hi, f16* __restrict__ lo, float4 v) {
  const float s = 0.015625f;  // 2^-6
  float a = v.x * s, b = v.y * s, c = v.z * s, d = v.w * s;
  f16x4v h = { (f16)a, (f16)b, (f16)c, (f16)d };
  f16x4v l = { (f16)(a - (float)h.x), (f16)(b - (float)h.y),
               (f16)(c - (float)h.z), (f16)(d - (float)h.w) };
  *(f16x4v*)hi = h;
  *(f16x4v*)lo = l;
}

__global__ __launch_bounds__(256) void k_aggregate(
    const float* __restrict__ x,
    const int* __restrict__ row_ptr,
    const int* __restrict__ records,
    f16* __restrict__ e0, f16* __restrict__ e1, f16* __restrict__ e2,
    f16* __restrict__ c2p, f16* __restrict__ c3p, f16* __restrict__ c4p)
{
  const size_t ND = (size_t)NN * DD;
  int wave = threadIdx.x >> 6;
  int lane = threadIdx.x & 63;
  int v = blockIdx.x * 4 + wave;
  if (v >= NN) return;
  int beg = row_ptr[v], end = row_ptr[v + 1];
  float4 a0 = make_float4(0, 0, 0, 0), a1 = a0, a2 = a0;
  float4 c2 = a0, c3 = a0, c4 = a0;
  for (int e = beg; e < end; ++e) {
    int rec = records[e];
    int src   = rec & 0x3FFFF;
    int hopm2 = ((rec >> 18) & 3) - 1;
    int et    = (rec >> 20) & 3;
    float4 xv = *(const float4*)(x + (size_t)src * DD + (lane << 2));
    if (et == 0)      f4add(a0, xv);
    else if (et == 1) f4add(a1, xv);
    else              f4add(a2, xv);
    if (hopm2 == 0)      f4add(c2, xv);
    else if (hopm2 == 1) f4add(c3, xv);
    else if (hopm2 == 2) f4add(c4, xv);
  }
  size_t o = (size_t)v * DD + (lane << 2);
  store_split(e0 + o, e0 + ND + o, a0);
  store_split(e1 + o, e1 + ND + o, a1);
  store_split(e2 + o, e2 + ND + o, a2);
  if (c2p) store_split(c2p + o, c2p + ND + o, c2);
  if (c3p) store_split(c3p + o, c3p + ND + o, c3);
  if (c4p) store_split(c4p + o, c4p + ND + o, c4);
}

// ---------------- split-fp16 MFMA GEMM + bias + relu + residual ----------------
// Tile 64(M) x 128(N), BK=32. 4 waves, each 32x64. Grid (313, 2) = 626 blocks.
// LDS swizzle: slot (row r, chunk q) holds global 16B chunk  q ^ ((r>>1)&3).

struct GemmArgs {
  const f16* A[6];     // hi at +0, lo at +N*D (f16 elems)
  const f16* W[6];     // transposed: hi at +0, lo at +D*D
  const float* bias[6];
  const int*   cnt[6];
  int nch;
  const float* x_in;
  float*       x_out;
};

__global__ __launch_bounds__(256, 4) void k_gemm(GemmArgs args) {
  __shared__ __align__(16) f16 sAhi[64 * BK];    // 4 KB
  __shared__ __align__(16) f16 sAlo[64 * BK];    // 4 KB
  __shared__ __align__(16) f16 sBhi[128 * BK];   // 8 KB
  __shared__ __align__(16) f16 sBlo[128 * BK];   // 8 KB
  const int tid = threadIdx.x;
  const int lane = tid & 63;
  const int wave = tid >> 6;
  const int wm = (wave >> 1) * 32;   // 0 or 32
  const int wn = (wave & 1) * 64;    // 0 or 64
  const int m0 = blockIdx.x * 64;
  const int n0 = blockIdx.y * 128;
  const int nch = args.nch;

  f32x4 acc[2][4];
#pragma unroll
  for (int i = 0; i < 2; i++)
#pragma unroll
    for (int j = 0; j < 4; j++) acc[i][j] = (f32x4){0.f, 0.f, 0.f, 0.f};

  // staging geometry: each tile row = 64 B (32 f16); thread loads one 16B chunk
  const int r = tid >> 2;                    // 0..63
  const int q = tid & 3;
  const int u = q ^ ((r >> 1) & 3);          // swizzled global chunk
  const int arow = min(m0 + r, NN - 1);
  const int brow0 = n0 + r;                  // < 256 always

  char* dAh = (char*)sAhi + tid * 16;
  char* dAl = (char*)sAlo + tid * 16;
  char* dBh0 = (char*)sBhi + tid * 16;  char* dBh1 = dBh0 + 4096;
  char* dBl0 = (char*)sBlo + tid * 16;  char* dBl1 = dBl0 + 4096;

  // fragment read offsets (f16 index), un-swizzling the chunk
  const int fr = lane & 15;
  const int gq = lane >> 4;                  // global k-chunk 0..3
  int offA[2], offB[4];
#pragma unroll
  for (int mi = 0; mi < 2; mi++) {
    int rr = wm + mi * 16 + fr;
    offA[mi] = rr * BK + ((gq ^ ((rr >> 1) & 3)) << 3);
  }
#pragma unroll
  for (int ni = 0; ni < 4; ni++) {
    int rr = wn + ni * 16 + fr;
    offB[ni] = rr * BK + ((gq ^ ((rr >> 1) & 3)) << 3);
  }

  for (int c = 0; c < nch; ++c) {
    const char* Ah = (const char*)args.A[c] + (size_t)arow * 512 + u * 16;
    const char* Al = Ah + (size_t)NN * DD * 2;                   // lo plane
    const char* Bh = (const char*)args.W[c] + (size_t)brow0 * 512 + u * 16;
    // rows brow0+64 at +32768 B; lo plane at +131072 B
#pragma unroll
    for (int kb = 0; kb < 512; kb += 64) {   // byte offset along k (8 iters)
      gll16(Ah + kb, dAh);
      gll16(Al + kb, dAl);
      gll16(Bh + kb, dBh0);
      gll16(Bh + 32768 + kb, dBh1);
      gll16(Bh + 131072 + kb, dBl0);
      gll16(Bh + 131072 + 32768 + kb, dBl1);
      __syncthreads();
      f16x8 fAh[2], fAl[2], fBh[4], fBl[4];
#pragma unroll
      for (int mi = 0; mi < 2; mi++) {
        fAh[mi] = *(const f16x8*)&sAhi[offA[mi]];
        fAl[mi] = *(const f16x8*)&sAlo[offA[mi]];
      }
#pragma unroll
      for (int ni = 0; ni < 4; ni++) {
        fBh[ni] = *(const f16x8*)&sBhi[offB[ni]];
        fBl[ni] = *(const f16x8*)&sBlo[offB[ni]];
      }
#pragma unroll
      for (int mi = 0; mi < 2; mi++)
#pragma unroll
        for (int ni = 0; ni < 4; ni++) {
          acc[mi][ni] = __builtin_amdgcn_mfma_f32_16x16x32_f16(fAh[mi], fBh[ni], acc[mi][ni], 0, 0, 0);
          acc[mi][ni] = __builtin_amdgcn_mfma_f32_16x16x32_f16(fAh[mi], fBl[ni], acc[mi][ni], 0, 0, 0);
          acc[mi][ni] = __builtin_amdgcn_mfma_f32_16x16x32_f16(fAl[mi], fBh[ni], acc[mi][ni], 0, 0, 0);
        }
      __syncthreads();
    }
  }

  // epilogue: out = x + relu(acc*2^-4 + sum_c cnt_c[row]*b_c[col])
  const float scale = 0.0625f;
  float bcol[4][6];
#pragma unroll
  for (int ni = 0; ni < 4; ni++) {
    int gcol = n0 + wn + ni * 16 + fr;
#pragma unroll
    for (int c = 0; c < 6; c++)
      bcol[ni][c] = (c < nch) ? args.bias[c][gcol] : 0.f;
  }
  const int rowq = (lane >> 4) * 4;
#pragma unroll
  for (int mi = 0; mi < 2; mi++) {
#pragma unroll
    for (int rI = 0; rI < 4; rI++) {
      int grow = m0 + wm + mi * 16 + rowq + rI;
      if (grow >= NN) continue;
      float cv[6];
#pragma unroll
      for (int c = 0; c < 6; c++)
        cv[c] = (c < nch) ? (float)args.cnt[c][grow] : 0.f;
      size_t rowoff = (size_t)grow * DD;
#pragma unroll
      for (int ni = 0; ni < 4; ni++) {
        int gcol = n0 + wn + ni * 16 + fr;
        float v = acc[mi][ni][rI] * scale;
#pragma unroll
        for (int c = 0; c < 6; c++) v += cv[c] * bcol[ni][c];
        float xv = args.x_in[rowoff + gcol];
        args.x_out[rowoff + gcol] = xv + fmaxf(v, 0.f);
      }
    }
  }
}

// ---------------- host ----------------

extern "C" void kernel_launch(void* const* d_in, const int* in_sizes, int n_in,
                              void* d_out, int out_size, void* d_ws, size_t ws_size,
                              hipStream_t stream) {
  const float* x      = (const float*)d_in[0];
  const int* edge_index = (const int*)d_in[1];
  const int* edge_attr  = (const int*)d_in[2];
  const float* W_edge = (const float*)d_in[3];
  const float* b_edge = (const float*)d_in[4];
  const float* W_hop  = (const float*)d_in[5];
  const float* b_hop  = (const float*)d_in[6];
  float* out = (float*)d_out;

  // workspace layout
  char* ws = (char*)d_ws;
  int* deg     = (int*)ws;            // N
  int* cnt     = deg + NN;            // 6N
  int* row_ptr = cnt + 6 * NN;        // N+1
  int* cursor  = row_ptr + (NN + 1);  // N
  int* records = cursor + NN;         // E
  size_t int_count = (size_t)NN + 6 * NN + (NN + 1) + NN + NE;
  const size_t ND = (size_t)NN * DD;
  f16* Wsplit = (f16*)(ws + ((int_count * 4 + 255) & ~(size_t)255));  // 24 * 131072 f16
  f16* aggBase = Wsplit + (size_t)24 * 131072;
  f16* agg[9];
  for (int i = 0; i < 9; i++) agg[i] = aggBase + (size_t)i * 2 * ND;
  f16** Cb = agg + 3;  // Cb[0..5]: C2_s0,C2_s1,C2_s2, C3_s0,C3_s1, C4_s0

  hipMemsetAsync(deg, 0, 7 * NN * sizeof(int), stream);
  hipMemcpyAsync(out, x, ND * sizeof(float), hipMemcpyDeviceToDevice, stream);

  k_hist<<<(NE + 255) / 256, 256, 0, stream>>>(edge_index, edge_attr, deg, cnt);
  k_scan<<<1, 1024, 0, stream>>>(deg, row_ptr, cursor);
  k_scatter<<<(NE + 255) / 256, 256, 0, stream>>>(edge_index, edge_attr, cursor, records);
  k_wsplit<<<dim3(256, 24), 256, 0, stream>>>(W_edge, W_hop, Wsplit);

  for (int t = 0; t < TT; ++t) {
    f16* c2p = (t <= 2) ? Cb[t]     : nullptr;
    f16* c3p = (t <= 1) ? Cb[3 + t] : nullptr;
    f16* c4p = (t == 0) ? Cb[5]     : nullptr;
    k_aggregate<<<NN / 4, 256, 0, stream>>>(out, row_ptr, records,
                                            agg[0], agg[1], agg[2], c2p, c3p, c4p);

    GemmArgs ga{};
    for (int e = 0; e < NT; ++e) {
      ga.A[e]    = agg[e];
      ga.W[e]    = Wsplit + (size_t)(t * NT + e) * 131072;
      ga.bias[e] = b_edge + (size_t)(t * NT + e) * DD;
      ga.cnt[e]  = cnt + (size_t)e * NN;
    }
    int nc = NT;
    for (int k = 2; k <= t + 1; ++k) {
      int s = t + 1 - k;
      ga.A[nc]    = (k == 2) ? Cb[s] : (k == 3) ? Cb[3 + s] : Cb[5];
      ga.W[nc]    = Wsplit + (size_t)(12 + t * 3 + (k - 2)) * 131072;
      ga.bias[nc] = b_hop + (size_t)(t * (TT - 1) + (k - 2)) * DD;
      ga.cnt[nc]  = cnt + (size_t)(3 + (k - 2)) * NN;
      nc++;
    }
    for (int c = nc; c < 6; ++c) {
      ga.A[c] = ga.A[0]; ga.W[c] = ga.W[0]; ga.bias[c] = ga.bias[0]; ga.cnt[c] = ga.cnt[0];
    }
    ga.nch = nc;
    ga.x_in = out;
    ga.x_out = out;
    k_gemm<<<dim3((NN + 63) / 64, 2), 256, 0, stream>>>(ga);
  }
}

// Round 4
// 698.157 us; speedup vs baseline: 1.7361x; 1.1868x over previous
//
#include <hip/hip_runtime.h>

// RelationalDelayGNNStage: N=20000, E=500000, D=256, T=4, NTYPES=3
// Round 4: plain-f16 operands (A scale 2^-6, W scale 2^4; error budget measured:
// fp32 floor absmax=32 of 174) + latency-oriented GEMM: TM=32,TN=128, 2-wave
// blocks, grid 1250 (4.9 blocks/CU). Aggregation gathers f16 x (half traffic).

#define NN 20000
#define NE 500000
#define DD 256
#define TT 4
#define NT 3
#define BK 32

typedef _Float16 f16;
typedef _Float16 f16x8 __attribute__((ext_vector_type(8)));
typedef _Float16 f16x4v __attribute__((ext_vector_type(4)));
typedef float f32x4 __attribute__((ext_vector_type(4)));

typedef const __attribute__((address_space(1))) void* gptr_t;
typedef __attribute__((address_space(3))) void* lptr_t;

__device__ __forceinline__ void gll16(const void* g, void* l) {
  __builtin_amdgcn_global_load_lds((gptr_t)g, (lptr_t)l, 16, 0, 0);
}

__device__ inline void f4add(float4& a, const float4 b) {
  a.x += b.x; a.y += b.y; a.z += b.z; a.w += b.w;
}

// ---------------- CSR build ----------------

__global__ void k_hist(const int* __restrict__ ei, const int* __restrict__ ea,
                       int* __restrict__ deg, int* __restrict__ cnt) {
  int e = blockIdx.x * 256 + threadIdx.x;
  if (e >= NE) return;
  int dst = ei[NE + e];
  atomicAdd(&deg[dst], 1);
  int hop = ea[2 * e];
  int et  = ea[2 * e + 1];
  atomicAdd(&cnt[et * NN + dst], 1);
  if (hop >= 2) atomicAdd(&cnt[(3 + hop - 2) * NN + dst], 1);
}

__global__ void k_scan(const int* __restrict__ deg, int* __restrict__ row_ptr,
                       int* __restrict__ cursor) {
  __shared__ int sdata[1024];
  __shared__ int s_run;
  int tid = threadIdx.x;
  if (tid == 0) s_run = 0;
  __syncthreads();
  for (int base = 0; base < NN; base += 1024) {
    int i = base + tid;
    int v = (i < NN) ? deg[i] : 0;
    sdata[tid] = v;
    __syncthreads();
    for (int off = 1; off < 1024; off <<= 1) {
      int t = (tid >= off) ? sdata[tid - off] : 0;
      __syncthreads();
      sdata[tid] += t;
      __syncthreads();
    }
    int excl = s_run + sdata[tid] - v;
    if (i < NN) { row_ptr[i] = excl; cursor[i] = excl; }
    __syncthreads();
    if (tid == 1023) s_run += sdata[1023];
    __syncthreads();
  }
  if (tid == 0) row_ptr[NN] = s_run;
}

__global__ void k_scatter(const int* __restrict__ ei, const int* __restrict__ ea,
                          int* __restrict__ cursor, int* __restrict__ records) {
  int e = blockIdx.x * 256 + threadIdx.x;
  if (e >= NE) return;
  int src = ei[e];
  int dst = ei[NE + e];
  int hop = ea[2 * e];
  int et  = ea[2 * e + 1];
  int pos = atomicAdd(&cursor[dst], 1);
  records[pos] = src | ((hop - 1) << 18) | (et << 20);
}

// ---------------- W: fp32 -> transposed f16, scale 2^4 ----------------

__global__ void k_wsplit(const float* __restrict__ W_edge, const float* __restrict__ W_hop,
                         f16* __restrict__ Wout) {
  int w = blockIdx.y;
  int flat = blockIdx.x * 256 + threadIdx.x;  // 0..65535
  int k = flat & 255, n = flat >> 8;
  const float* src = (w < 12) ? (W_edge + (size_t)w * 65536)
                              : (W_hop + (size_t)(w - 12) * 65536);
  Wout[(size_t)w * 65536 + n * 256 + k] = (f16)(src[k * 256 + n] * 16.0f);
}

// ---------------- x fp32 -> f16 copy ----------------

__global__ void k_xcast(const float* __restrict__ x, f16* __restrict__ xh) {
  size_t i = (size_t)(blockIdx.x * 256 + threadIdx.x) * 4;
  float4 v = *(const float4*)(x + i);
  f16x4v h = { (f16)v.x, (f16)v.y, (f16)v.z, (f16)v.w };
  *(f16x4v*)(xh + i) = h;
}

// ---------------- aggregation: one wave per node, f16 gather ----------------

__device__ inline void store_h(f16* __restrict__ p, float4 v) {
  const float s = 0.015625f;  // 2^-6
  f16x4v h = { (f16)(v.x * s), (f16)(v.y * s), (f16)(v.z * s), (f16)(v.w * s) };
  *(f16x4v*)p = h;
}

__global__ __launch_bounds__(256) void k_aggregate(
    const f16* __restrict__ xh,
    const int* __restrict__ row_ptr,
    const int* __restrict__ records,
    f16* __restrict__ e0, f16* __restrict__ e1, f16* __restrict__ e2,
    f16* __restrict__ c2p, f16* __restrict__ c3p, f16* __restrict__ c4p)
{
  int wave = threadIdx.x >> 6;
  int lane = threadIdx.x & 63;
  int v = blockIdx.x * 4 + wave;
  if (v >= NN) return;
  int beg = row_ptr[v], end = row_ptr[v + 1];
  float4 a0 = make_float4(0, 0, 0, 0), a1 = a0, a2 = a0;
  float4 c2 = a0, c3 = a0, c4 = a0;
  for (int e = beg; e < end; ++e) {
    int rec = records[e];
    int src   = rec & 0x3FFFF;
    int hopm2 = ((rec >> 18) & 3) - 1;
    int et    = (rec >> 20) & 3;
    f16x4v hv = *(const f16x4v*)(xh + (size_t)src * DD + (lane << 2));
    float4 xv = make_float4((float)hv.x, (float)hv.y, (float)hv.z, (float)hv.w);
    if (et == 0)      f4add(a0, xv);
    else if (et == 1) f4add(a1, xv);
    else              f4add(a2, xv);
    if (hopm2 == 0)      f4add(c2, xv);
    else if (hopm2 == 1) f4add(c3, xv);
    else if (hopm2 == 2) f4add(c4, xv);
  }
  size_t o = (size_t)v * DD + (lane << 2);
  store_h(e0 + o, a0);
  store_h(e1 + o, a1);
  store_h(e2 + o, a2);
  if (c2p) store_h(c2p + o, c2);
  if (c3p) store_h(c3p + o, c3);
  if (c4p) store_h(c4p + o, c4);
}

// ---------------- f16 MFMA GEMM + bias + relu + residual ----------------
// Tile 32(M) x 128(N), BK=32. 2 waves (each 32x64). Grid (625, 2) = 1250 blocks.
// LDS swizzle: slot (row r, chunk q) holds global 16B chunk  q ^ ((r>>1)&3).

struct GemmArgs {
  const f16* A[6];     // aggregates, scale 2^-6
  const f16* W[6];     // transposed, scale 2^4
  const float* bias[6];
  const int*   cnt[6];
  int nch;
  const float* x_in;
  float*       x_out;
  f16*         xh_out;
};

__global__ __launch_bounds__(128, 4) void k_gemm(GemmArgs args) {
  __shared__ __align__(16) f16 sA[32 * BK];    // 2 KB
  __shared__ __align__(16) f16 sB[128 * BK];   // 8 KB
  const int tid = threadIdx.x;
  const int lane = tid & 63;
  const int wave = tid >> 6;
  const int wn = wave * 64;
  const int m0 = blockIdx.x * 32;     // 625 * 32 = 20000 exact, no guards
  const int n0 = blockIdx.y * 128;
  const int nch = args.nch;

  f32x4 acc[2][4];
#pragma unroll
  for (int i = 0; i < 2; i++)
#pragma unroll
    for (int j = 0; j < 4; j++) acc[i][j] = (f32x4){0.f, 0.f, 0.f, 0.f};

  // staging: tile row = 64 B; 128 threads: A 1 chunk each, B 4 chunks each
  const int r = tid >> 2;                    // 0..31
  const int q = tid & 3;
  const int u = q ^ ((r >> 1) & 3);          // swizzled global chunk (same for r+32j)

  char* dA = (char*)sA + tid * 16;
  char* dB = (char*)sB + tid * 16;           // row r+32j at +j*2048

  // fragment read offsets (f16 units), un-swizzling
  const int fr = lane & 15;
  const int gq = lane >> 4;
  int offA[2], offB[4];
#pragma unroll
  for (int mi = 0; mi < 2; mi++) {
    int rr = mi * 16 + fr;
    offA[mi] = rr * BK + ((gq ^ ((rr >> 1) & 3)) << 3);
  }
#pragma unroll
  for (int ni = 0; ni < 4; ni++) {
    int rr = wn + ni * 16 + fr;
    offB[ni] = rr * BK + ((gq ^ ((rr >> 1) & 3)) << 3);
  }

  for (int c = 0; c < nch; ++c) {
    const char* pa = (const char*)args.A[c] + (size_t)(m0 + r) * 512 + u * 16;
    const char* pb = (const char*)args.W[c] + (size_t)(n0 + r) * 512 + u * 16;
#pragma unroll
    for (int kb = 0; kb < 512; kb += 64) {   // 8 K-iters of BK=32
      gll16(pa + kb, dA);
      gll16(pb + kb,         dB);
      gll16(pb + 16384 + kb, dB + 2048);
      gll16(pb + 32768 + kb, dB + 4096);
      gll16(pb + 49152 + kb, dB + 6144);
      __syncthreads();
      f16x8 fA[2], fB[4];
#pragma unroll
      for (int mi = 0; mi < 2; mi++) fA[mi] = *(const f16x8*)&sA[offA[mi]];
#pragma unroll
      for (int ni = 0; ni < 4; ni++) fB[ni] = *(const f16x8*)&sB[offB[ni]];
#pragma unroll
      for (int mi = 0; mi < 2; mi++)
#pragma unroll
        for (int ni = 0; ni < 4; ni++)
          acc[mi][ni] = __builtin_amdgcn_mfma_f32_16x16x32_f16(fA[mi], fB[ni], acc[mi][ni], 0, 0, 0);
      __syncthreads();
    }
  }

  // epilogue: out = x + relu(acc*4 + sum_c cnt_c[row]*b_c[col]);  4 = 2^6 * 2^-4
  float bcol[4][6];
#pragma unroll
  for (int ni = 0; ni < 4; ni++) {
    int gcol = n0 + wn + ni * 16 + fr;
#pragma unroll
    for (int c = 0; c < 6; c++)
      bcol[ni][c] = (c < nch) ? args.bias[c][gcol] : 0.f;
  }
  const int rowq = (lane >> 4) * 4;
#pragma unroll
  for (int mi = 0; mi < 2; mi++) {
#pragma unroll
    for (int rI = 0; rI < 4; rI++) {
      int grow = m0 + mi * 16 + rowq + rI;
      float cv[6];
#pragma unroll
      for (int c = 0; c < 6; c++)
        cv[c] = (c < nch) ? (float)args.cnt[c][grow] : 0.f;
      size_t rowoff = (size_t)grow * DD;
#pragma unroll
      for (int ni = 0; ni < 4; ni++) {
        int gcol = n0 + wn + ni * 16 + fr;
        float v = acc[mi][ni][rI] * 4.0f;
#pragma unroll
        for (int c = 0; c < 6; c++) v += cv[c] * bcol[ni][c];
        float outv = args.x_in[rowoff + gcol] + fmaxf(v, 0.f);
        args.x_out[rowoff + gcol] = outv;
        args.xh_out[rowoff + gcol] = (f16)outv;
      }
    }
  }
}

// ---------------- host ----------------

extern "C" void kernel_launch(void* const* d_in, const int* in_sizes, int n_in,
                              void* d_out, int out_size, void* d_ws, size_t ws_size,
                              hipStream_t stream) {
  const float* x      = (const float*)d_in[0];
  const int* edge_index = (const int*)d_in[1];
  const int* edge_attr  = (const int*)d_in[2];
  const float* W_edge = (const float*)d_in[3];
  const float* b_edge = (const float*)d_in[4];
  const float* W_hop  = (const float*)d_in[5];
  const float* b_hop  = (const float*)d_in[6];
  float* out = (float*)d_out;

  // workspace layout
  char* ws = (char*)d_ws;
  int* deg     = (int*)ws;            // N
  int* cnt     = deg + NN;            // 6N
  int* row_ptr = cnt + 6 * NN;        // N+1
  int* cursor  = row_ptr + (NN + 1);  // N
  int* records = cursor + NN;         // E
  size_t int_count = (size_t)NN + 6 * NN + (NN + 1) + NN + NE;
  const size_t ND = (size_t)NN * DD;
  f16* Wsplit = (f16*)(ws + ((int_count * 4 + 255) & ~(size_t)255));  // 24 * 65536 f16
  f16* xh = Wsplit + (size_t)24 * 65536;                              // N*D f16
  f16* aggBase = xh + ND;
  f16* agg[9];
  for (int i = 0; i < 9; i++) agg[i] = aggBase + (size_t)i * ND;
  f16** Cb = agg + 3;  // Cb[0..5]: C2_s0,C2_s1,C2_s2, C3_s0,C3_s1, C4_s0

  hipMemsetAsync(deg, 0, 7 * NN * sizeof(int), stream);
  hipMemcpyAsync(out, x, ND * sizeof(float), hipMemcpyDeviceToDevice, stream);

  k_hist<<<(NE + 255) / 256, 256, 0, stream>>>(edge_index, edge_attr, deg, cnt);
  k_scan<<<1, 1024, 0, stream>>>(deg, row_ptr, cursor);
  k_scatter<<<(NE + 255) / 256, 256, 0, stream>>>(edge_index, edge_attr, cursor, records);
  k_wsplit<<<dim3(256, 24), 256, 0, stream>>>(W_edge, W_hop, Wsplit);
  k_xcast<<<ND / 1024, 256, 0, stream>>>(x, xh);

  for (int t = 0; t < TT; ++t) {
    f16* c2p = (t <= 2) ? Cb[t]     : nullptr;
    f16* c3p = (t <= 1) ? Cb[3 + t] : nullptr;
    f16* c4p = (t == 0) ? Cb[5]     : nullptr;
    k_aggregate<<<NN / 4, 256, 0, stream>>>(xh, row_ptr, records,
                                            agg[0], agg[1], agg[2], c2p, c3p, c4p);

    GemmArgs ga{};
    for (int e = 0; e < NT; ++e) {
      ga.A[e]    = agg[e];
      ga.W[e]    = Wsplit + (size_t)(t * NT + e) * 65536;
      ga.bias[e] = b_edge + (size_t)(t * NT + e) * DD;
      ga.cnt[e]  = cnt + (size_t)e * NN;
    }
    int nc = NT;
    for (int k = 2; k <= t + 1; ++k) {
      int s = t + 1 - k;
      ga.A[nc]    = (k == 2) ? Cb[s] : (k == 3) ? Cb[3 + s] : Cb[5];
      ga.W[nc]    = Wsplit + (size_t)(12 + t * 3 + (k - 2)) * 65536;
      ga.bias[nc] = b_hop + (size_t)(t * (TT - 1) + (k - 2)) * DD;
      ga.cnt[nc]  = cnt + (size_t)(3 + (k - 2)) * NN;
      nc++;
    }
    for (int c = nc; c < 6; ++c) {
      ga.A[c] = ga.A[0]; ga.W[c] = ga.W[0]; ga.bias[c] = ga.bias[0]; ga.cnt[c] = ga.cnt[0];
    }
    ga.nch = nc;
    ga.x_in = out;
    ga.x_out = out;
    ga.xh_out = xh;
    k_gemm<<<dim3(625, 2), 128, 0, stream>>>(ga);
  }
}